// Round 12
// baseline (1149.000 us; speedup 1.0000x reference)
//
#include <hip/hip_runtime.h>
#include <math.h>

#ifndef M_PI
#define M_PI 3.14159265358979323846
#endif

#define LEN   4096
#define NB    32
#define NH    64
#define NF    2048   // modes stored (bins 0..2047)
#define NLAYER 4

__device__ __forceinline__ float2 cmul(float2 a, float2 b) {
    return make_float2(a.x*b.x - a.y*b.y, a.x*b.y + a.y*b.x);
}

// powers W[k] = w1^k, k=0..15, via squaring ladder (max 3 chained muls)
__device__ __forceinline__ void twpow16(float2 w1, float2 W[16]) {
    W[0] = make_float2(1.0f, 0.0f);
    W[1] = w1;
    W[2] = cmul(w1, w1);
    W[3] = cmul(W[2], W[1]);
    W[4] = cmul(W[2], W[2]);
    W[5] = cmul(W[4], W[1]);
    W[6] = cmul(W[4], W[2]);
    W[7] = cmul(W[4], W[3]);
    W[8] = cmul(W[4], W[4]);
    W[9]  = cmul(W[8], W[1]);
    W[10] = cmul(W[8], W[2]);
    W[11] = cmul(W[8], W[3]);
    W[12] = cmul(W[8], W[4]);
    W[13] = cmul(W[8], W[5]);
    W[14] = cmul(W[8], W[6]);
    W[15] = cmul(W[8], W[7]);
}

// async global -> LDS, 16 B per lane (dest = wave-uniform base + lane*16)
__device__ __forceinline__ void gll16(const void* g, void* l) {
    __builtin_amdgcn_global_load_lds(
        (const __attribute__((address_space(1))) void*)g,
        (__attribute__((address_space(3))) void*)l, 16, 0, 0);
}

// ---------------------------------------------------------------------------
// twiddle table: tw[k] = exp(-2*pi*i*k/4096), k = 0..4095 (full circle)
__global__ __launch_bounds__(256) void fill_tw(float2* __restrict__ tw) {
    int k = blockIdx.x * 256 + threadIdx.x;
    if (k < 4096) {
        double ang = -2.0 * M_PI * (double)k / 4096.0;
        tw[k] = make_float2((float)cos(ang), (float)sin(ang));
    }
}

// ---------------------------------------------------------------------------
// conv2 weight transpose: w2t[l][i][o] = w2[l][o][i]  (4 layers x 64 x 64)
__global__ __launch_bounds__(256) void w2t_k(
        const float* __restrict__ w2, float* __restrict__ w2t) {
    int idx = blockIdx.x * 256 + threadIdx.x;    // 0..16383
    int l = idx >> 12;
    int r = idx & 4095;
    int o = r >> 6, i = r & 63;
    w2t[l * 4096 + i * 64 + o] = w2[idx];
}

// ---------------------------------------------------------------------------
// in-register 16-point DIF FFT. Natural-order input z[n]; output Z[k] lands
// in z[BR16[k]] (4-bit reversal, compile-time). INV=true: conjugated twiddles.
#define BR16_INIT const int BR[16] = {0,8,4,12,2,10,6,14,1,9,5,13,3,11,7,15}

template<bool INV>
__device__ __forceinline__ void fft16(float2 z[16]) {
    const float S  = INV ? 1.0f : -1.0f;
    const float C1 = 0.9238795325112867f, S1 = 0.3826834323650898f;
    const float C2 = 0.7071067811865476f;
    const float2 W16[8] = {{1.f,0.f},{C1,S*S1},{C2,S*C2},{S1,S*C1},
                           {0.f,S},{-S1,S*C1},{-C2,S*C2},{-C1,S*S1}};
    const float2 W8[4]  = {{1.f,0.f},{C2,S*C2},{0.f,S},{-C2,S*C2}};
    #pragma unroll
    for (int i = 0; i < 8; ++i) {
        float2 u = z[i], v = z[i+8];
        z[i]   = make_float2(u.x+v.x, u.y+v.y);
        float2 d = make_float2(u.x-v.x, u.y-v.y);
        z[i+8] = cmul(d, W16[i]);
    }
    #pragma unroll
    for (int h = 0; h < 16; h += 8)
        #pragma unroll
        for (int i = 0; i < 4; ++i) {
            float2 u = z[h+i], v = z[h+i+4];
            z[h+i]   = make_float2(u.x+v.x, u.y+v.y);
            float2 d = make_float2(u.x-v.x, u.y-v.y);
            z[h+i+4] = cmul(d, W8[i]);
        }
    #pragma unroll
    for (int h = 0; h < 16; h += 4) {
        { float2 u = z[h],   v = z[h+2];
          z[h]   = make_float2(u.x+v.x, u.y+v.y);
          z[h+2] = make_float2(u.x-v.x, u.y-v.y); }
        { float2 u = z[h+1], v = z[h+3];
          z[h+1] = make_float2(u.x+v.x, u.y+v.y);
          float2 d = make_float2(u.x-v.x, u.y-v.y);
          z[h+3] = make_float2(-S*d.y, S*d.x); }      // d * (0,S)
    }
    #pragma unroll
    for (int h = 0; h < 16; h += 2) {
        float2 u = z[h], v = z[h+1];
        z[h]   = make_float2(u.x+v.x, u.y+v.y);
        z[h+1] = make_float2(u.x-v.x, u.y-v.y);
    }
}

// ---------------------------------------------------------------------------
// encoder
__global__ __launch_bounds__(256) void encoder_k(
        const float* __restrict__ x, const float* __restrict__ u,
        const float* __restrict__ ew, const float* __restrict__ eb,
        float* __restrict__ v) {
    int tid = blockIdx.x * 256 + threadIdx.x;
    int b = tid >> 12;
    int l = tid & (LEN - 1);
    float xv = x[(size_t)b * LEN + l];
    float u0 = u[((size_t)b * 3 + 0) * LEN + l];
    float u1 = u[((size_t)b * 3 + 1) * LEN + l];
    float u2 = u[((size_t)b * 3 + 2) * LEN + l];
    for (int h = 0; h < NH; ++h) {
        float a = eb[h] + ew[h*4+0]*xv + ew[h*4+1]*u0 + ew[h*4+2]*u1 + ew[h*4+3]*u2;
        v[((size_t)b * NH + h) * LEN + l] = a;
    }
}

// ---------------------------------------------------------------------------
// forward FFT, radix-16^3 four-step, gather-free twiddles (round-11 verified).
__global__ __launch_bounds__(256) void fft_fwd_k(
        const float* __restrict__ vin, float2* __restrict__ Xt,
        const float2* __restrict__ tw) {
    __shared__ float2 lds[4352];                 // 34816 B
    BR16_INIT;
    int p = blockIdx.x;                          // 0..1023
    const float* s1 = vin + (size_t)(2*p)   * LEN;
    const float* s2 = vin + (size_t)(2*p+1) * LEN;
    int t = threadIdx.x;                         // = b
    float2 z[16];
    #pragma unroll
    for (int a = 0; a < 16; ++a)
        z[a] = make_float2(s1[a*256 + t], s2[a*256 + t]);
    fft16<false>(z);
    {
        float2 Wp[16];
        twpow16(tw[t], Wp);                      // W4096^(t*ka), coalesced base
        #pragma unroll
        for (int r = 0; r < 16; ++r) {
            int ka = BR[r];
            lds[ka*256 + t] = cmul(z[r], Wp[ka]);
        }
    }
    __syncthreads();
    int ka = t >> 4, bp = t & 15;                // round-2 role (k_a, b')
    #pragma unroll
    for (int a2 = 0; a2 < 16; ++a2)
        z[a2] = lds[ka*256 + a2*16 + bp];        // b = a2*16 + b'
    __syncthreads();
    fft16<false>(z);
    {
        float2 Wq[16];
        twpow16(tw[16*bp], Wq);                  // W256^(bp*kap), 16-bcast base
        #pragma unroll
        for (int r = 0; r < 16; ++r) {
            int kap = BR[r];
            lds[kap*272 + ka*17 + bp] = cmul(z[r], Wq[kap]);
        }
    }
    __syncthreads();
    int kap2 = t >> 4, ka2 = t & 15;             // round-3 role (k_a', k_a)
    #pragma unroll
    for (int b2 = 0; b2 < 16; ++b2)
        z[b2] = lds[kap2*272 + ka2*17 + b2];
    __syncthreads();
    fft16<false>(z);
    #pragma unroll
    for (int r = 0; r < 16; ++r)
        lds[t + 256*BR[r]] = z[r];
    __syncthreads();
    float2* d1 = Xt + (size_t)(2*p)   * NF;
    float2* d2 = Xt + (size_t)(2*p+1) * NF;
    for (int j = 0; j < 8; ++j) {
        int f = t + j * 256;                     // 0..2047
        float2 Zf = lds[f];
        float2 Zm = lds[(4096 - f) & 4095];
        d1[f] = make_float2(0.5f * (Zf.x + Zm.x), 0.5f * (Zf.y - Zm.y));
        d2[f] = make_float2(0.5f * (Zf.y + Zm.y), 0.5f * (Zm.x - Zf.x));
    }
}

// ---------------------------------------------------------------------------
// inverse FFT, radix-16^3 four-step, gather-free twiddles. SINGLE-spectrum
// input again (round-12: partial-Y scheme retired; -24 MB/layer read).
__global__ __launch_bounds__(256) void fft_inv_k(
        const float2* __restrict__ Yt, float* __restrict__ sout,
        const float2* __restrict__ tw,
        const float* __restrict__ sb0, const float* __restrict__ sb1,
        const float* __restrict__ sb2, int layer) {
    __shared__ float2 lds[4352];
    BR16_INIT;
    int p = blockIdx.x;                          // 0..1023
    int o = (2 * p) & (NH - 1);                  // even o
    const float2* s1 = Yt + (size_t)(2*p)   * NF;
    const float2* s2 = Yt + (size_t)(2*p+1) * NF;
    int t = threadIdx.x;
    float2 z[16];
    #pragma unroll
    for (int a = 0; a < 16; ++a) {
        int f = a * 256 + t;
        float2 zf;
        if (f < 2048) {
            float2 y1 = s1[f];
            float2 y2 = s2[f];
            if (f == 0) zf = make_float2(y1.x, y2.x);
            else        zf = make_float2(y1.x - y2.y, y1.y + y2.x);
        } else if (f == 2048) {
            zf = make_float2(0.0f, 0.0f);
        } else {
            int m = 4096 - f;                    // 1..2047
            float2 y1 = s1[m];
            float2 y2 = s2[m];
            zf = make_float2(y1.x + y2.y, y2.x - y1.y);  // conj(Y1)+i*conj(Y2)
        }
        z[a] = zf;
    }
    fft16<true>(z);
    {
        float2 w1 = tw[t]; w1.y = -w1.y;         // conj base -> conj powers
        float2 Wp[16];
        twpow16(w1, Wp);
        #pragma unroll
        for (int r = 0; r < 16; ++r) {
            int ka = BR[r];
            lds[ka*256 + t] = cmul(z[r], Wp[ka]);
        }
    }
    __syncthreads();
    int ka = t >> 4, bp = t & 15;
    #pragma unroll
    for (int a2 = 0; a2 < 16; ++a2)
        z[a2] = lds[ka*256 + a2*16 + bp];
    __syncthreads();
    fft16<true>(z);
    {
        float2 w16 = tw[16*bp]; w16.y = -w16.y;
        float2 Wq[16];
        twpow16(w16, Wq);
        #pragma unroll
        for (int r = 0; r < 16; ++r) {
            int kap = BR[r];
            lds[kap*272 + ka*17 + bp] = cmul(z[r], Wq[kap]);
        }
    }
    __syncthreads();
    int kap2 = t >> 4, ka2 = t & 15;
    #pragma unroll
    for (int b2 = 0; b2 < 16; ++b2)
        z[b2] = lds[kap2*272 + ka2*17 + b2];
    fft16<true>(z);
    float bias1 = sb0[layer*NH+o]   + sb1[layer*NH+o]   + sb2[layer*NH+o];
    float bias2 = sb0[layer*NH+o+1] + sb1[layer*NH+o+1] + sb2[layer*NH+o+1];
    float* d1 = sout + (size_t)(2*p)   * LEN;
    float* d2 = sout + (size_t)(2*p+1) * LEN;
    const float sc = 1.0f / 4096.0f;
    #pragma unroll
    for (int r = 0; r < 16; ++r) {
        int l = t + 256 * BR[r];
        d1[l] = z[r].x * sc + bias1;
        d2[l] = z[r].y * sc + bias2;
    }
}

// ---------------------------------------------------------------------------
// spectral matmul v9: SINGLE summed-Y output (partial-Y retired: -48 MB/layer
// round-trip). Weff = w2 + [f<1024] w1 + [f<512] w0, summed in registers.
//  - X staged via global_load_lds ring (R7/R9 verified addressing+swizzle)
//  - W reg-staged: loads ISSUED before compute, summed + ds_written AFTER
//    (hides HBM latency under the FMA block), 2-buffer, 1 barrier/chunk
//  - XCD-resident sibling groups kept: ftile=(tl&3)*64+(tl>>2)*8+xcd puts all
//    4 og-siblings on one XCD AND interleaves heavy tiles every 4th slot, so
//    every XCD gets an identical heavy/medium/light mix (no imbalance).
// Grid 1024, LDS 24 KB -> 6 blocks/CU.
__global__ __launch_bounds__(256) void specmm_k(
        const float2* __restrict__ X, float2* __restrict__ Y,
        const float* __restrict__ w0, const float* __restrict__ w1,
        const float* __restrict__ w2, int layer) {
    __shared__ float2 Xb[2][1024];    // [buf][i4][b32][slot4][e2]  8 KB each
    __shared__ float2 Wb[2][512];     // [buf][i4][o16][slot4][e2]  4 KB each

    int n   = blockIdx.x;             // 0..1023
    int xcd = n & 7;                  // dispatch round-robin -> XCD id
    int s   = n >> 3;                 // slot within XCD, 0..127
    int og  = s & 3;                  // siblings adjacent -> same-XCD X reuse
    int tl  = s >> 2;                 // 0..31
    int ftile = (tl & 3) * 64 + (tl >> 2) * 8 + xcd;   // bijective, 0..255
    int f0 = ftile * 8;
    const bool has1 = (f0 < 1024);
    const bool has0 = (f0 < 512);

    const float2* w2b = (const float2*)w2 + (size_t)layer * NH * NH * 2048;
    const float2* w1b = (const float2*)w1 + (size_t)layer * NH * NH * 1024;
    const float2* w0b = (const float2*)w0 + (size_t)layer * NH * NH * 512;

    int t  = threadIdx.x;
    int ff = t & 7;                   // compute: f offset 0..7
    int u  = t >> 3;                  // 0..31
    int b0  = (u & 7) * 4;            // compute: 4 b rows
    int oo0 = (u >> 3) * 4;           // compute: 4 o cols (== wave id)

    // staging roles: wave wv stages i-row wv of each 4-i chunk
    const int wv = t >> 6;            // wave 0..3
    const int ln = t & 63;
    const int bs = ln >> 2;           // 0..15 (b-sub for X / o-sub for W)
    const int sl = ln & 3;            // slot 0..3

    float2 acc[4][4];
    #pragma unroll
    for (int bb = 0; bb < 4; ++bb)
        #pragma unroll
        for (int oo = 0; oo < 4; ++oo)
            acc[bb][oo] = make_float2(0.0f, 0.0f);

    // per-lane global source pointers (X pre-swizzled, R7-verified)
    const float2* gx0; const float2* gx1;
    {
        int b = bs;                                    // half 0
        int fp = sl ^ ((b >> 2) & 3);
        gx0 = X + ((size_t)b * NH + wv) * 2048 + f0 + 2*fp;
        b = 16 + bs;                                   // half 1
        fp = sl ^ ((b >> 2) & 3);
        gx1 = X + ((size_t)b * NH + wv) * 2048 + f0 + 2*fp;
    }
    const size_t io = (size_t)wv * NH + og * 16 + bs;
    const float2* gw2 = w2b + io * 2048 + f0 + 2*sl;
    const float2* gw1 = w1b + io * 1024 + f0 + 2*sl;
    const float2* gw0 = w0b + io * 512  + f0 + 2*sl;

    #define STAGE_X(ic_, nb_)                                                   \
    {                                                                           \
        gll16(gx0 + (size_t)(ic_)*4*2048, &Xb[nb_][(wv*32 +  0)*8]);            \
        gll16(gx1 + (size_t)(ic_)*4*2048, &Xb[nb_][(wv*32 + 16)*8]);            \
    }
    float2 l2a, l2b, l1a, l1b, l0a, l0b;
    #define WISSUE(ic_)                                                         \
    {                                                                           \
        const float2* p2 = gw2 + (size_t)(ic_)*256*2048;                        \
        l2a = p2[0]; l2b = p2[1];                                               \
        if (has1) { const float2* p1 = gw1 + (size_t)(ic_)*256*1024;            \
                    l1a = p1[0]; l1b = p1[1]; }                                 \
        if (has0) { const float2* p0 = gw0 + (size_t)(ic_)*256*512;             \
                    l0a = p0[0]; l0b = p0[1]; }                                 \
    }
    #define WSUM_STORE(nb_)                                                     \
    {                                                                           \
        float2 wa = l2a, wc = l2b;                                              \
        if (has1) { wa.x += l1a.x; wa.y += l1a.y; wc.x += l1b.x; wc.y += l1b.y; } \
        if (has0) { wa.x += l0a.x; wa.y += l0a.y; wc.x += l0b.x; wc.y += l0b.y; } \
        Wb[nb_][wv*128 + ln*2]     = wa;                                        \
        Wb[nb_][wv*128 + ln*2 + 1] = wc;                                        \
    }

    WISSUE(0);
    STAGE_X(0, 0);
    WSUM_STORE(0);
    __syncthreads();                   // implicit vmcnt(0): X dma + W loads done
    int buf = 0;
    for (int ic = 0; ic < 16; ++ic) {
        if (ic < 15) { STAGE_X(ic + 1, buf ^ 1); WISSUE(ic + 1); }  // async
        #pragma unroll
        for (int ii = 0; ii < 4; ++ii) {
            float2 xr[4], wr[4];
            #pragma unroll
            for (int bb = 0; bb < 4; ++bb) {
                int b = b0 + bb;
                int slot = (ff >> 1) ^ ((b >> 2) & 3);
                xr[bb] = Xb[buf][((ii*32 + b)*4 + slot)*2 + (ff & 1)];
            }
            #pragma unroll
            for (int oo = 0; oo < 4; ++oo)
                wr[oo] = Wb[buf][((ii*16 + oo0 + oo)*4 + (ff >> 1))*2 + (ff & 1)];
            #pragma unroll
            for (int bb = 0; bb < 4; ++bb)
                #pragma unroll
                for (int oo = 0; oo < 4; ++oo) {
                    acc[bb][oo].x += xr[bb].x * wr[oo].x - xr[bb].y * wr[oo].y;
                    acc[bb][oo].y += xr[bb].x * wr[oo].y + xr[bb].y * wr[oo].x;
                }
        }
        if (ic < 15) WSUM_STORE(buf ^ 1);   // waitcnt lands here, under compute
        __syncthreads();                    // drains gll dma; publishes Wb
        buf ^= 1;
    }
    #undef STAGE_X
    #undef WISSUE
    #undef WSUM_STORE

    // direct coalesced stores (lanes ff-contiguous -> 64B f-runs)
    #pragma unroll
    for (int bb = 0; bb < 4; ++bb)
        #pragma unroll
        for (int oo = 0; oo < 4; ++oo)
            Y[((size_t)(b0 + bb) * NH + og * 16 + oo0 + oo) * 2048 + f0 + ff] = acc[bb][oo];
}

// ---------------------------------------------------------------------------
// fused conv1+gelu+conv2+residual v2 (round-10 verified): 4-acc conv1 dot,
// pre-transposed w2t rows. Last layer: decoder fused, writes out directly.
__global__ __launch_bounds__(256) void conv_fused_k(
        const float* __restrict__ s,
        const float* __restrict__ c1w, const float* __restrict__ c1b,
        const float* __restrict__ w2t, const float* __restrict__ c2b,
        int layer, float* __restrict__ v,
        const float* __restrict__ dw, const float* __restrict__ db,
        float* __restrict__ out, int last) {
    int tid = blockIdx.x * 256 + threadIdx.x;
    int b = tid >> 12;
    int l = tid & (LEN - 1);
    float xr[NH];
    #pragma unroll
    for (int i = 0; i < NH; ++i) xr[i] = s[((size_t)b * NH + i) * LEN + l];
    const float* w1 = c1w + (size_t)layer * NH * NH;
    const float* b1 = c1b + layer * NH;
    const float* w2 = w2t + (size_t)layer * NH * NH;   // [i][o] rows
    const float* b2 = c2b + layer * NH;
    float acc2[NH];
    #pragma unroll
    for (int o = 0; o < NH; ++o) acc2[o] = b2[o];
    for (int i = 0; i < NH; ++i) {               // not unrolled: keeps I-size sane
        const float* wr = w1 + i * NH;
        float a0 = 0.0f, a1 = 0.0f, a2 = 0.0f, a3 = 0.0f;
        #pragma unroll
        for (int k = 0; k < NH; k += 4) {
            a0 += wr[k]     * xr[k];
            a1 += wr[k + 1] * xr[k + 1];
            a2 += wr[k + 2] * xr[k + 2];
            a3 += wr[k + 3] * xr[k + 3];
        }
        float acc = b1[i] + ((a0 + a1) + (a2 + a3));
        float cc = 0.7978845608028654f * (acc + 0.044715f * acc * acc * acc);
        float e  = __expf(2.0f * cc);
        float th = 1.0f - 2.0f / (e + 1.0f);
        float h  = 0.5f * acc * (1.0f + th);
        const float* wc = w2 + i * NH;
        #pragma unroll
        for (int o = 0; o < NH; ++o) acc2[o] += wc[o] * h;
    }
    if (!last) {
        #pragma unroll
        for (int o = 0; o < NH; ++o) {
            size_t idx = ((size_t)b * NH + o) * LEN + l;
            v[idx] = v[idx] + acc2[o];
        }
    } else {
        float acc = db[0];
        #pragma unroll
        for (int o = 0; o < NH; ++o) {
            size_t idx = ((size_t)b * NH + o) * LEN + l;
            acc += dw[o] * (v[idx] + acc2[o]);
        }
        out[(size_t)b * LEN + l] = acc;
    }
}

// ---------------------------------------------------------------------------
extern "C" void kernel_launch(void* const* d_in, const int* in_sizes, int n_in,
                              void* d_out, int out_size, void* d_ws, size_t ws_size,
                              hipStream_t stream) {
    const float* u_in   = (const float*)d_in[0];
    const float* x_in   = (const float*)d_in[1];
    const float* enc_w  = (const float*)d_in[2];
    const float* enc_b  = (const float*)d_in[3];
    const float* dec_w  = (const float*)d_in[4];
    const float* dec_b  = (const float*)d_in[5];
    const float* conv1w = (const float*)d_in[6];
    const float* conv1b = (const float*)d_in[7];
    const float* conv2w = (const float*)d_in[8];
    const float* conv2b = (const float*)d_in[9];
    const float* sw0    = (const float*)d_in[10];
    const float* sb0    = (const float*)d_in[11];
    const float* sw1    = (const float*)d_in[12];
    const float* sb1    = (const float*)d_in[13];
    const float* sw2    = (const float*)d_in[14];
    const float* sb2    = (const float*)d_in[15];

    const size_t CPLX = (size_t)2048 * 2048;
    const size_t REAL = (size_t)NB * NH * LEN;
    char* base = (char*)d_ws;
    float2* tw   = (float2*)base;                // 4096 entries = 32768 B
    float2* bufA = (float2*)(base + 32768);      // X: [row][2048]
    float2* bufB = bufA + CPLX;                  // Y: [row][2048]
    float*  sbuf = (float*)(bufB + CPLX);
    float*  vbuf = sbuf + REAL;
    float*  w2tb = vbuf + REAL;                  // transposed conv2 weights, 64 KB
    size_t need = 32768 + 2 * CPLX * sizeof(float2) + 2 * REAL * sizeof(float)
                + (size_t)NLAYER * NH * NH * sizeof(float);
    if (ws_size < need) return;

    fill_tw<<<16, 256, 0, stream>>>(tw);
    w2t_k<<<64, 256, 0, stream>>>(conv2w, w2tb);
    encoder_k<<<(NB * LEN) / 256, 256, 0, stream>>>(x_in, u_in, enc_w, enc_b, vbuf);

    for (int l = 0; l < NLAYER; ++l) {
        fft_fwd_k  <<<NB * NH / 2, 256, 0, stream>>>(vbuf, bufA, tw);
        specmm_k   <<<1024, 256, 0, stream>>>(bufA, bufB, sw0, sw1, sw2, l);
        fft_inv_k  <<<NB * NH / 2, 256, 0, stream>>>(bufB, sbuf, tw,
                                                     sb0, sb1, sb2, l);
        conv_fused_k<<<(NB * LEN) / 256, 256, 0, stream>>>(sbuf, conv1w, conv1b,
                                                           w2tb, conv2b, l, vbuf,
                                                           dec_w, dec_b, (float*)d_out,
                                                           l == NLAYER - 1);
    }
}

// Round 13
// 1059.758 us; speedup vs baseline: 1.0842x; 1.0842x over previous
//
#include <hip/hip_runtime.h>
#include <math.h>

#ifndef M_PI
#define M_PI 3.14159265358979323846
#endif

#define LEN   4096
#define NB    32
#define NH    64
#define NF    2048   // modes stored (bins 0..2047)
#define NLAYER 4

__device__ __forceinline__ float2 cmul(float2 a, float2 b) {
    return make_float2(a.x*b.x - a.y*b.y, a.x*b.y + a.y*b.x);
}

// powers W[k] = w1^k, k=0..15, via squaring ladder (max 3 chained muls)
__device__ __forceinline__ void twpow16(float2 w1, float2 W[16]) {
    W[0] = make_float2(1.0f, 0.0f);
    W[1] = w1;
    W[2] = cmul(w1, w1);
    W[3] = cmul(W[2], W[1]);
    W[4] = cmul(W[2], W[2]);
    W[5] = cmul(W[4], W[1]);
    W[6] = cmul(W[4], W[2]);
    W[7] = cmul(W[4], W[3]);
    W[8] = cmul(W[4], W[4]);
    W[9]  = cmul(W[8], W[1]);
    W[10] = cmul(W[8], W[2]);
    W[11] = cmul(W[8], W[3]);
    W[12] = cmul(W[8], W[4]);
    W[13] = cmul(W[8], W[5]);
    W[14] = cmul(W[8], W[6]);
    W[15] = cmul(W[8], W[7]);
}

// async global -> LDS, 16 B per lane (dest = wave-uniform base + lane*16)
__device__ __forceinline__ void gll16(const void* g, void* l) {
    __builtin_amdgcn_global_load_lds(
        (const __attribute__((address_space(1))) void*)g,
        (__attribute__((address_space(3))) void*)l, 16, 0, 0);
}

// ---------------------------------------------------------------------------
// twiddle table: tw[k] = exp(-2*pi*i*k/4096), k = 0..4095 (full circle)
__global__ __launch_bounds__(256) void fill_tw(float2* __restrict__ tw) {
    int k = blockIdx.x * 256 + threadIdx.x;
    if (k < 4096) {
        double ang = -2.0 * M_PI * (double)k / 4096.0;
        tw[k] = make_float2((float)cos(ang), (float)sin(ang));
    }
}

// ---------------------------------------------------------------------------
// conv2 weight transpose: w2t[l][i][o] = w2[l][o][i]  (4 layers x 64 x 64)
__global__ __launch_bounds__(256) void w2t_k(
        const float* __restrict__ w2, float* __restrict__ w2t) {
    int idx = blockIdx.x * 256 + threadIdx.x;    // 0..16383
    int l = idx >> 12;
    int r = idx & 4095;
    int o = r >> 6, i = r & 63;
    w2t[l * 4096 + i * 64 + o] = w2[idx];
}

// ---------------------------------------------------------------------------
// in-register 16-point DIF FFT. Natural-order input z[n]; output Z[k] lands
// in z[BR16[k]] (4-bit reversal, compile-time). INV=true: conjugated twiddles.
#define BR16_INIT const int BR[16] = {0,8,4,12,2,10,6,14,1,9,5,13,3,11,7,15}

template<bool INV>
__device__ __forceinline__ void fft16(float2 z[16]) {
    const float S  = INV ? 1.0f : -1.0f;
    const float C1 = 0.9238795325112867f, S1 = 0.3826834323650898f;
    const float C2 = 0.7071067811865476f;
    const float2 W16[8] = {{1.f,0.f},{C1,S*S1},{C2,S*C2},{S1,S*C1},
                           {0.f,S},{-S1,S*C1},{-C2,S*C2},{-C1,S*S1}};
    const float2 W8[4]  = {{1.f,0.f},{C2,S*C2},{0.f,S},{-C2,S*C2}};
    #pragma unroll
    for (int i = 0; i < 8; ++i) {
        float2 u = z[i], v = z[i+8];
        z[i]   = make_float2(u.x+v.x, u.y+v.y);
        float2 d = make_float2(u.x-v.x, u.y-v.y);
        z[i+8] = cmul(d, W16[i]);
    }
    #pragma unroll
    for (int h = 0; h < 16; h += 8)
        #pragma unroll
        for (int i = 0; i < 4; ++i) {
            float2 u = z[h+i], v = z[h+i+4];
            z[h+i]   = make_float2(u.x+v.x, u.y+v.y);
            float2 d = make_float2(u.x-v.x, u.y-v.y);
            z[h+i+4] = cmul(d, W8[i]);
        }
    #pragma unroll
    for (int h = 0; h < 16; h += 4) {
        { float2 u = z[h],   v = z[h+2];
          z[h]   = make_float2(u.x+v.x, u.y+v.y);
          z[h+2] = make_float2(u.x-v.x, u.y-v.y); }
        { float2 u = z[h+1], v = z[h+3];
          z[h+1] = make_float2(u.x+v.x, u.y+v.y);
          float2 d = make_float2(u.x-v.x, u.y-v.y);
          z[h+3] = make_float2(-S*d.y, S*d.x); }      // d * (0,S)
    }
    #pragma unroll
    for (int h = 0; h < 16; h += 2) {
        float2 u = z[h], v = z[h+1];
        z[h]   = make_float2(u.x+v.x, u.y+v.y);
        z[h+1] = make_float2(u.x-v.x, u.y-v.y);
    }
}

// ---------------------------------------------------------------------------
// encoder
__global__ __launch_bounds__(256) void encoder_k(
        const float* __restrict__ x, const float* __restrict__ u,
        const float* __restrict__ ew, const float* __restrict__ eb,
        float* __restrict__ v) {
    int tid = blockIdx.x * 256 + threadIdx.x;
    int b = tid >> 12;
    int l = tid & (LEN - 1);
    float xv = x[(size_t)b * LEN + l];
    float u0 = u[((size_t)b * 3 + 0) * LEN + l];
    float u1 = u[((size_t)b * 3 + 1) * LEN + l];
    float u2 = u[((size_t)b * 3 + 2) * LEN + l];
    for (int h = 0; h < NH; ++h) {
        float a = eb[h] + ew[h*4+0]*xv + ew[h*4+1]*u0 + ew[h*4+2]*u1 + ew[h*4+3]*u2;
        v[((size_t)b * NH + h) * LEN + l] = a;
    }
}

// ---------------------------------------------------------------------------
// forward FFT, radix-16^3 four-step, gather-free twiddles (round-11 verified).
__global__ __launch_bounds__(256) void fft_fwd_k(
        const float* __restrict__ vin, float2* __restrict__ Xt,
        const float2* __restrict__ tw) {
    __shared__ float2 lds[4352];                 // 34816 B
    BR16_INIT;
    int p = blockIdx.x;                          // 0..1023
    const float* s1 = vin + (size_t)(2*p)   * LEN;
    const float* s2 = vin + (size_t)(2*p+1) * LEN;
    int t = threadIdx.x;                         // = b
    float2 z[16];
    #pragma unroll
    for (int a = 0; a < 16; ++a)
        z[a] = make_float2(s1[a*256 + t], s2[a*256 + t]);
    fft16<false>(z);
    {
        float2 Wp[16];
        twpow16(tw[t], Wp);                      // W4096^(t*ka), coalesced base
        #pragma unroll
        for (int r = 0; r < 16; ++r) {
            int ka = BR[r];
            lds[ka*256 + t] = cmul(z[r], Wp[ka]);
        }
    }
    __syncthreads();
    int ka = t >> 4, bp = t & 15;                // round-2 role (k_a, b')
    #pragma unroll
    for (int a2 = 0; a2 < 16; ++a2)
        z[a2] = lds[ka*256 + a2*16 + bp];        // b = a2*16 + b'
    __syncthreads();
    fft16<false>(z);
    {
        float2 Wq[16];
        twpow16(tw[16*bp], Wq);                  // W256^(bp*kap), 16-bcast base
        #pragma unroll
        for (int r = 0; r < 16; ++r) {
            int kap = BR[r];
            lds[kap*272 + ka*17 + bp] = cmul(z[r], Wq[kap]);
        }
    }
    __syncthreads();
    int kap2 = t >> 4, ka2 = t & 15;             // round-3 role (k_a', k_a)
    #pragma unroll
    for (int b2 = 0; b2 < 16; ++b2)
        z[b2] = lds[kap2*272 + ka2*17 + b2];
    __syncthreads();
    fft16<false>(z);
    #pragma unroll
    for (int r = 0; r < 16; ++r)
        lds[t + 256*BR[r]] = z[r];
    __syncthreads();
    float2* d1 = Xt + (size_t)(2*p)   * NF;
    float2* d2 = Xt + (size_t)(2*p+1) * NF;
    for (int j = 0; j < 8; ++j) {
        int f = t + j * 256;                     // 0..2047
        float2 Zf = lds[f];
        float2 Zm = lds[(4096 - f) & 4095];
        d1[f] = make_float2(0.5f * (Zf.x + Zm.x), 0.5f * (Zf.y - Zm.y));
        d2[f] = make_float2(0.5f * (Zf.y + Zm.y), 0.5f * (Zm.x - Zf.x));
    }
}

// ---------------------------------------------------------------------------
// inverse FFT, radix-16^3 four-step, gather-free twiddles, single-spectrum
// input (round-12 verified).
__global__ __launch_bounds__(256) void fft_inv_k(
        const float2* __restrict__ Yt, float* __restrict__ sout,
        const float2* __restrict__ tw,
        const float* __restrict__ sb0, const float* __restrict__ sb1,
        const float* __restrict__ sb2, int layer) {
    __shared__ float2 lds[4352];
    BR16_INIT;
    int p = blockIdx.x;                          // 0..1023
    int o = (2 * p) & (NH - 1);                  // even o
    const float2* s1 = Yt + (size_t)(2*p)   * NF;
    const float2* s2 = Yt + (size_t)(2*p+1) * NF;
    int t = threadIdx.x;
    float2 z[16];
    #pragma unroll
    for (int a = 0; a < 16; ++a) {
        int f = a * 256 + t;
        float2 zf;
        if (f < 2048) {
            float2 y1 = s1[f];
            float2 y2 = s2[f];
            if (f == 0) zf = make_float2(y1.x, y2.x);
            else        zf = make_float2(y1.x - y2.y, y1.y + y2.x);
        } else if (f == 2048) {
            zf = make_float2(0.0f, 0.0f);
        } else {
            int m = 4096 - f;                    // 1..2047
            float2 y1 = s1[m];
            float2 y2 = s2[m];
            zf = make_float2(y1.x + y2.y, y2.x - y1.y);  // conj(Y1)+i*conj(Y2)
        }
        z[a] = zf;
    }
    fft16<true>(z);
    {
        float2 w1 = tw[t]; w1.y = -w1.y;         // conj base -> conj powers
        float2 Wp[16];
        twpow16(w1, Wp);
        #pragma unroll
        for (int r = 0; r < 16; ++r) {
            int ka = BR[r];
            lds[ka*256 + t] = cmul(z[r], Wp[ka]);
        }
    }
    __syncthreads();
    int ka = t >> 4, bp = t & 15;
    #pragma unroll
    for (int a2 = 0; a2 < 16; ++a2)
        z[a2] = lds[ka*256 + a2*16 + bp];
    __syncthreads();
    fft16<true>(z);
    {
        float2 w16 = tw[16*bp]; w16.y = -w16.y;
        float2 Wq[16];
        twpow16(w16, Wq);
        #pragma unroll
        for (int r = 0; r < 16; ++r) {
            int kap = BR[r];
            lds[kap*272 + ka*17 + bp] = cmul(z[r], Wq[kap]);
        }
    }
    __syncthreads();
    int kap2 = t >> 4, ka2 = t & 15;
    #pragma unroll
    for (int b2 = 0; b2 < 16; ++b2)
        z[b2] = lds[kap2*272 + ka2*17 + b2];
    fft16<true>(z);
    float bias1 = sb0[layer*NH+o]   + sb1[layer*NH+o]   + sb2[layer*NH+o];
    float bias2 = sb0[layer*NH+o+1] + sb1[layer*NH+o+1] + sb2[layer*NH+o+1];
    float* d1 = sout + (size_t)(2*p)   * LEN;
    float* d2 = sout + (size_t)(2*p+1) * LEN;
    const float sc = 1.0f / 4096.0f;
    #pragma unroll
    for (int r = 0; r < 16; ++r) {
        int l = t + 256 * BR[r];
        d1[l] = z[r].x * sc + bias1;
        d2[l] = z[r].y * sc + bias2;
    }
}

// ---------------------------------------------------------------------------
// spectral matmul v9 (round-12 verified): single summed-Y, gll X-ring,
// reg-staged W, XCD-resident sibling groups.
__global__ __launch_bounds__(256) void specmm_k(
        const float2* __restrict__ X, float2* __restrict__ Y,
        const float* __restrict__ w0, const float* __restrict__ w1,
        const float* __restrict__ w2, int layer) {
    __shared__ float2 Xb[2][1024];    // [buf][i4][b32][slot4][e2]  8 KB each
    __shared__ float2 Wb[2][512];     // [buf][i4][o16][slot4][e2]  4 KB each

    int n   = blockIdx.x;             // 0..1023
    int xcd = n & 7;                  // dispatch round-robin -> XCD id
    int s   = n >> 3;                 // slot within XCD, 0..127
    int og  = s & 3;                  // siblings adjacent -> same-XCD X reuse
    int tl  = s >> 2;                 // 0..31
    int ftile = (tl & 3) * 64 + (tl >> 2) * 8 + xcd;   // bijective, 0..255
    int f0 = ftile * 8;
    const bool has1 = (f0 < 1024);
    const bool has0 = (f0 < 512);

    const float2* w2b = (const float2*)w2 + (size_t)layer * NH * NH * 2048;
    const float2* w1b = (const float2*)w1 + (size_t)layer * NH * NH * 1024;
    const float2* w0b = (const float2*)w0 + (size_t)layer * NH * NH * 512;

    int t  = threadIdx.x;
    int ff = t & 7;                   // compute: f offset 0..7
    int u  = t >> 3;                  // 0..31
    int b0  = (u & 7) * 4;            // compute: 4 b rows
    int oo0 = (u >> 3) * 4;           // compute: 4 o cols (== wave id)

    // staging roles: wave wv stages i-row wv of each 4-i chunk
    const int wv = t >> 6;            // wave 0..3
    const int ln = t & 63;
    const int bs = ln >> 2;           // 0..15 (b-sub for X / o-sub for W)
    const int sl = ln & 3;            // slot 0..3

    float2 acc[4][4];
    #pragma unroll
    for (int bb = 0; bb < 4; ++bb)
        #pragma unroll
        for (int oo = 0; oo < 4; ++oo)
            acc[bb][oo] = make_float2(0.0f, 0.0f);

    // per-lane global source pointers (X pre-swizzled, R7-verified)
    const float2* gx0; const float2* gx1;
    {
        int b = bs;                                    // half 0
        int fp = sl ^ ((b >> 2) & 3);
        gx0 = X + ((size_t)b * NH + wv) * 2048 + f0 + 2*fp;
        b = 16 + bs;                                   // half 1
        fp = sl ^ ((b >> 2) & 3);
        gx1 = X + ((size_t)b * NH + wv) * 2048 + f0 + 2*fp;
    }
    const size_t io = (size_t)wv * NH + og * 16 + bs;
    const float2* gw2 = w2b + io * 2048 + f0 + 2*sl;
    const float2* gw1 = w1b + io * 1024 + f0 + 2*sl;
    const float2* gw0 = w0b + io * 512  + f0 + 2*sl;

    #define STAGE_X(ic_, nb_)                                                   \
    {                                                                           \
        gll16(gx0 + (size_t)(ic_)*4*2048, &Xb[nb_][(wv*32 +  0)*8]);            \
        gll16(gx1 + (size_t)(ic_)*4*2048, &Xb[nb_][(wv*32 + 16)*8]);            \
    }
    float2 l2a, l2b, l1a, l1b, l0a, l0b;
    #define WISSUE(ic_)                                                         \
    {                                                                           \
        const float2* p2 = gw2 + (size_t)(ic_)*256*2048;                        \
        l2a = p2[0]; l2b = p2[1];                                               \
        if (has1) { const float2* p1 = gw1 + (size_t)(ic_)*256*1024;            \
                    l1a = p1[0]; l1b = p1[1]; }                                 \
        if (has0) { const float2* p0 = gw0 + (size_t)(ic_)*256*512;             \
                    l0a = p0[0]; l0b = p0[1]; }                                 \
    }
    #define WSUM_STORE(nb_)                                                     \
    {                                                                           \
        float2 wa = l2a, wc = l2b;                                              \
        if (has1) { wa.x += l1a.x; wa.y += l1a.y; wc.x += l1b.x; wc.y += l1b.y; } \
        if (has0) { wa.x += l0a.x; wa.y += l0a.y; wc.x += l0b.x; wc.y += l0b.y; } \
        Wb[nb_][wv*128 + ln*2]     = wa;                                        \
        Wb[nb_][wv*128 + ln*2 + 1] = wc;                                        \
    }

    WISSUE(0);
    STAGE_X(0, 0);
    WSUM_STORE(0);
    __syncthreads();                   // implicit vmcnt(0): X dma + W loads done
    int buf = 0;
    for (int ic = 0; ic < 16; ++ic) {
        if (ic < 15) { STAGE_X(ic + 1, buf ^ 1); WISSUE(ic + 1); }  // async
        #pragma unroll
        for (int ii = 0; ii < 4; ++ii) {
            float2 xr[4], wr[4];
            #pragma unroll
            for (int bb = 0; bb < 4; ++bb) {
                int b = b0 + bb;
                int slot = (ff >> 1) ^ ((b >> 2) & 3);
                xr[bb] = Xb[buf][((ii*32 + b)*4 + slot)*2 + (ff & 1)];
            }
            #pragma unroll
            for (int oo = 0; oo < 4; ++oo)
                wr[oo] = Wb[buf][((ii*16 + oo0 + oo)*4 + (ff >> 1))*2 + (ff & 1)];
            #pragma unroll
            for (int bb = 0; bb < 4; ++bb)
                #pragma unroll
                for (int oo = 0; oo < 4; ++oo) {
                    acc[bb][oo].x += xr[bb].x * wr[oo].x - xr[bb].y * wr[oo].y;
                    acc[bb][oo].y += xr[bb].x * wr[oo].y + xr[bb].y * wr[oo].x;
                }
        }
        if (ic < 15) WSUM_STORE(buf ^ 1);   // waitcnt lands here, under compute
        __syncthreads();                    // drains gll dma; publishes Wb
        buf ^= 1;
    }
    #undef STAGE_X
    #undef WISSUE
    #undef WSUM_STORE

    // direct coalesced stores (lanes ff-contiguous -> 64B f-runs)
    #pragma unroll
    for (int bb = 0; bb < 4; ++bb)
        #pragma unroll
        for (int oo = 0; oo < 4; ++oo)
            Y[((size_t)(b0 + bb) * NH + og * 16 + oo0 + oo) * 2048 + f0 + ff] = acc[bb][oo];
}

// ---------------------------------------------------------------------------
// conv v3: the conv pair as an LDS-tiled GEMM pair.
//   h[i][l] = gelu(W1 . S + b1);  V[o][l] += W2t^T . h + b2
// R12's conv ran 1-thread-per-(b,l): 512 blocks = 2 waves/SIMD with ~155 VGPR
// (xr[64]+acc2[64]) -- occupancy-pinned. Here: block = (b, 64-col l-tile),
// 2048 blocks, each thread a 4x4 sub-tile per GEMM (~64 VGPR) -> 16 waves/CU.
// Columns l = tl + 16*dl keep v/out stores 64B-contiguous per lane group.
// Last layer: decoder fused via LDS o-group reduction.
__global__ __launch_bounds__(256) void conv_fused_k(
        const float* __restrict__ s,
        const float* __restrict__ c1w, const float* __restrict__ c1b,
        const float* __restrict__ w2t, const float* __restrict__ c2b,
        int layer, float* __restrict__ v,
        const float* __restrict__ dw, const float* __restrict__ db,
        float* __restrict__ out, int last) {
    __shared__ float Ss[64][65];      // S-tile  [ch][l]  (+1 pad)
    __shared__ float Hs[64][65];      // H-tile  [i][l]
    int blk = blockIdx.x;
    int b  = blk >> 6;                // batch
    int l0 = (blk & 63) * 64;         // column tile base
    int t  = threadIdx.x;

    // stage S-tile: 4096 elements, 16/thread, coalesced 256B row-runs
    const float* sb = s + (size_t)b * NH * LEN + l0;
    #pragma unroll
    for (int j = 0; j < 16; ++j) {
        int e = t + 256 * j;
        Ss[e >> 6][e & 63] = sb[(size_t)(e >> 6) * LEN + (e & 63)];
    }
    __syncthreads();

    const float* w1 = c1w + (size_t)layer * NH * NH;
    const float* b1 = c1b + layer * NH;
    int ti = t >> 4;                  // i-group (GEMM1) / o-group (GEMM2)
    int tl = t & 15;                  // l-group: l = tl + 16*dl

    // ---- GEMM1: h = gelu(W1.S + b1), 4i x 4l per thread ----
    {
        float acc[4][4];
        #pragma unroll
        for (int di = 0; di < 4; ++di) {
            float bias = b1[ti*4 + di];
            #pragma unroll
            for (int dl = 0; dl < 4; ++dl) acc[di][dl] = bias;
        }
        for (int k4 = 0; k4 < 64; k4 += 4) {
            float sv[4][4];
            #pragma unroll
            for (int kk = 0; kk < 4; ++kk)
                #pragma unroll
                for (int dl = 0; dl < 4; ++dl)
                    sv[kk][dl] = Ss[k4 + kk][tl + 16*dl];
            #pragma unroll
            for (int di = 0; di < 4; ++di) {
                float4 wv = *(const float4*)&w1[(ti*4 + di)*64 + k4];
                #pragma unroll
                for (int dl = 0; dl < 4; ++dl)
                    acc[di][dl] += wv.x*sv[0][dl] + wv.y*sv[1][dl]
                                 + wv.z*sv[2][dl] + wv.w*sv[3][dl];
            }
        }
        #pragma unroll
        for (int di = 0; di < 4; ++di)
            #pragma unroll
            for (int dl = 0; dl < 4; ++dl) {
                float a  = acc[di][dl];
                float cc = 0.7978845608028654f * (a + 0.044715f * a * a * a);
                float e  = __expf(2.0f * cc);
                float th = 1.0f - 2.0f / (e + 1.0f);
                Hs[ti*4 + di][tl + 16*dl] = 0.5f * a * (1.0f + th);
            }
    }
    __syncthreads();

    // ---- GEMM2: acc2 = W2t^T.h + b2, 4o x 4l per thread ----
    const float* w2 = w2t + (size_t)layer * NH * NH;   // [i][o] rows
    const float* b2 = c2b + layer * NH;
    float acc2[4][4];
    #pragma unroll
    for (int dq = 0; dq < 4; ++dq) {
        float bias = b2[ti*4 + dq];
        #pragma unroll
        for (int dl = 0; dl < 4; ++dl) acc2[dq][dl] = bias;
    }
    for (int i = 0; i < 64; ++i) {
        float hv[4];
        #pragma unroll
        for (int dl = 0; dl < 4; ++dl) hv[dl] = Hs[i][tl + 16*dl];
        #pragma unroll
        for (int dq = 0; dq < 4; ++dq) {
            float wv = w2[i*64 + ti*4 + dq];
            #pragma unroll
            for (int dl = 0; dl < 4; ++dl) acc2[dq][dl] += wv * hv[dl];
        }
    }

    if (!last) {
        #pragma unroll
        for (int dq = 0; dq < 4; ++dq)
            #pragma unroll
            for (int dl = 0; dl < 4; ++dl) {
                size_t idx = ((size_t)b * NH + ti*4 + dq) * LEN + l0 + tl + 16*dl;
                v[idx] = v[idx] + acc2[dq][dl];
            }
    } else {
        // decoder: out[b][l] = db + sum_o dw[o]*(v+acc2); o split over 16
        // ti-groups -> LDS reduce (reuse Ss, dead after GEMM1+barrier).
        float part[4];
        #pragma unroll
        for (int dl = 0; dl < 4; ++dl) part[dl] = 0.0f;
        #pragma unroll
        for (int dq = 0; dq < 4; ++dq) {
            float w = dw[ti*4 + dq];
            #pragma unroll
            for (int dl = 0; dl < 4; ++dl) {
                size_t idx = ((size_t)b * NH + ti*4 + dq) * LEN + l0 + tl + 16*dl;
                part[dl] += w * (v[idx] + acc2[dq][dl]);
            }
        }
        #pragma unroll
        for (int dl = 0; dl < 4; ++dl) Ss[tl + 16*dl][ti] = part[dl];
        __syncthreads();
        if (t < 64) {
            float acc = db[0];
            #pragma unroll
            for (int g = 0; g < 16; ++g) acc += Ss[t][g];
            out[(size_t)b * LEN + l0 + t] = acc;
        }
    }
}

// ---------------------------------------------------------------------------
extern "C" void kernel_launch(void* const* d_in, const int* in_sizes, int n_in,
                              void* d_out, int out_size, void* d_ws, size_t ws_size,
                              hipStream_t stream) {
    const float* u_in   = (const float*)d_in[0];
    const float* x_in   = (const float*)d_in[1];
    const float* enc_w  = (const float*)d_in[2];
    const float* enc_b  = (const float*)d_in[3];
    const float* dec_w  = (const float*)d_in[4];
    const float* dec_b  = (const float*)d_in[5];
    const float* conv1w = (const float*)d_in[6];
    const float* conv1b = (const float*)d_in[7];
    const float* conv2w = (const float*)d_in[8];
    const float* conv2b = (const float*)d_in[9];
    const float* sw0    = (const float*)d_in[10];
    const float* sb0    = (const float*)d_in[11];
    const float* sw1    = (const float*)d_in[12];
    const float* sb1    = (const float*)d_in[13];
    const float* sw2    = (const float*)d_in[14];
    const float* sb2    = (const float*)d_in[15];

    const size_t CPLX = (size_t)2048 * 2048;
    const size_t REAL = (size_t)NB * NH * LEN;
    char* base = (char*)d_ws;
    float2* tw   = (float2*)base;                // 4096 entries = 32768 B
    float2* bufA = (float2*)(base + 32768);      // X: [row][2048]
    float2* bufB = bufA + CPLX;                  // Y: [row][2048]
    float*  sbuf = (float*)(bufB + CPLX);
    float*  vbuf = sbuf + REAL;
    float*  w2tb = vbuf + REAL;                  // transposed conv2 weights, 64 KB
    size_t need = 32768 + 2 * CPLX * sizeof(float2) + 2 * REAL * sizeof(float)
                + (size_t)NLAYER * NH * NH * sizeof(float);
    if (ws_size < need) return;

    fill_tw<<<16, 256, 0, stream>>>(tw);
    w2t_k<<<64, 256, 0, stream>>>(conv2w, w2tb);
    encoder_k<<<(NB * LEN) / 256, 256, 0, stream>>>(x_in, u_in, enc_w, enc_b, vbuf);

    for (int l = 0; l < NLAYER; ++l) {
        fft_fwd_k  <<<NB * NH / 2, 256, 0, stream>>>(vbuf, bufA, tw);
        specmm_k   <<<1024, 256, 0, stream>>>(bufA, bufB, sw0, sw1, sw2, l);
        fft_inv_k  <<<NB * NH / 2, 256, 0, stream>>>(bufB, sbuf, tw,
                                                     sb0, sb1, sb2, l);
        conv_fused_k<<<NB * 64, 256, 0, stream>>>(sbuf, conv1w, conv1b,
                                                  w2tb, conv2b, l, vbuf,
                                                  dec_w, dec_b, (float*)d_out,
                                                  l == NLAYER - 1);
    }
}